// Round 5
// baseline (184.971 us; speedup 1.0000x reference)
//
#include <hip/hip_runtime.h>

// SelfMixing: CG tensor-product self-coupling, diagonal in channel.
// V6: barrier-FREE wave-private pipeline.
//  - Each wave owns 2 complete rows: its xs/os LDS slices are private ->
//    NO __syncthreads anywhere (no vmcnt(0) barrier drains, the m97 stall).
//  - Persistent blocks (1024 x 4 groups, grid-stride) with reg-staged
//    prefetch (T14): group g+1's 3 float4 loads issue before g's compute,
//    hiding ~900cyc HBM latency under compute+store.
//  - Per-lane mix/keep coefficients hoisted out of the group loop (lane's
//    channel identity is loop-invariant): ~21 fewer global loads per group.
//  - Lanes 0-31 do class-B jobs, 32-63 class-C (same cost as V5's wave split).

namespace cgc {

struct cplx { double re, im; };
constexpr cplx cmul(cplx a, cplx b){ return {a.re*b.re - a.im*b.im, a.re*b.im + a.im*b.re}; }

constexpr double cfact(int n){ double r = 1.0; for (int i = 2; i <= n; ++i) r *= i; return r; }
constexpr double cabsd(double x){ return x < 0 ? -x : x; }

constexpr double csqrtd(double x){
  if (x <= 0.0) return 0.0;
  double g = x > 1.0 ? x : 1.0;
  for (int i = 0; i < 48; ++i) g = 0.5*(g + x/g);
  return g;
}

constexpr double SQRT2 = csqrtd(2.0);

constexpr double cg_complex(int l1,int m1,int l2,int m2,int l3,int m3){
  if (m1 + m2 != m3) return 0.0;
  int lo = l1 > l2 ? l1 - l2 : l2 - l1;
  if (l3 < lo || l3 > l1 + l2) return 0.0;
  double pre = csqrtd((2*l3+1) * cfact(l1+l2-l3)*cfact(l1-l2+l3)*cfact(-l1+l2+l3)/cfact(l1+l2+l3+1));
  pre *= csqrtd(cfact(l1+m1)*cfact(l1-m1)*cfact(l2+m2)*cfact(l2-m2)*cfact(l3+m3)*cfact(l3-m3));
  int kmin = 0;
  if (l2-l3-m1 > kmin) kmin = l2-l3-m1;
  if (l1-l3+m2 > kmin) kmin = l1-l3+m2;
  int kmax = l1+l2-l3;
  if (l1-m1 < kmax) kmax = l1-m1;
  if (l2+m2 < kmax) kmax = l2+m2;
  double s = 0.0;
  for (int k = kmin; k <= kmax; ++k){
    double d = cfact(k)*cfact(l1+l2-l3-k)*cfact(l1-m1-k)*cfact(l2+m2-k)
             * cfact(l3-l2+m1+k)*cfact(l3-l1-m2+k);
    s += ((k & 1) ? -1.0 : 1.0) / d;
  }
  return pre * s;
}

// U[r][c]: rows = real m' (r = m'+l), cols = complex m (c = m+l)
constexpr cplx Uent(int l, int r, int c){
  int m = r - l;
  if (m > 0){
    if (c ==  m + l) return { ((m & 1) ? -1.0 : 1.0)/SQRT2, 0.0 };
    if (c == -m + l) return { 1.0/SQRT2, 0.0 };
    return {0.0, 0.0};
  } else if (m == 0){
    if (c == l) return {1.0, 0.0};
    return {0.0, 0.0};
  } else {
    int ma = -m;
    if (c ==  m + l) return { 0.0, 1.0/SQRT2 };                       // 1j/sqrt2
    if (c == -m + l) return { 0.0, -(((ma & 1) ? -1.0 : 1.0))/SQRT2 };// -1j*(-1)^m/sqrt2
    return {0.0, 0.0};
  }
}

template<int L1,int L2,int L3>
struct CGData { float w[(2*L1+1)*(2*L2+1)*(2*L3+1)]; };

template<int L1,int L2,int L3>
constexpr CGData<L1,L2,L3> make_cg(){
  constexpr int D1 = 2*L1+1, D2 = 2*L2+1, D3 = 2*L3+1;
  cplx U1[D1*D1] = {}; cplx U2[D2*D2] = {}; cplx U3c[D3*D3] = {};
  for (int r = 0; r < D1; ++r) for (int c = 0; c < D1; ++c) U1[r*D1+c] = Uent(L1, r, c);
  for (int r = 0; r < D2; ++r) for (int c = 0; c < D2; ++c) U2[r*D2+c] = Uent(L2, r, c);
  for (int r = 0; r < D3; ++r) for (int c = 0; c < D3; ++c){
    cplx u = Uent(L3, r, c); u.im = -u.im; U3c[r*D3+c] = u;
  }
  double Cc[D1*D2*D3] = {};
  for (int m1 = -L1; m1 <= L1; ++m1)
    for (int m2 = -L2; m2 <= L2; ++m2){
      int m3 = m1 + m2;
      if (m3 < -L3 || m3 > L3) continue;
      Cc[((m1+L1)*D2 + (m2+L2))*D3 + (m3+L3)] = cg_complex(L1,m1,L2,m2,L3,m3);
    }
  double re[D1*D2*D3] = {}; double im[D1*D2*D3] = {};
  for (int a = 0; a < D1; ++a)
    for (int b = 0; b < D2; ++b)
      for (int c = 0; c < D3; ++c){
        double sre = 0.0, sim = 0.0;
        for (int m = 0; m < D1; ++m)
          for (int n = 0; n < D2; ++n){
            int o = m + n - L1 - L2 + L3;   // only nonzero Cc slice
            if (o < 0 || o >= D3) continue;
            double cc = Cc[(m*D2+n)*D3 + o];
            if (cc == 0.0) continue;
            cplx p = cmul(cmul(U1[a*D1+m], U2[b*D2+n]), U3c[c*D3+o]);
            sre += p.re * cc; sim += p.im * cc;
          }
        re[(a*D2+b)*D3+c] = sre; im[(a*D2+b)*D3+c] = sim;
      }
  double mre = 0.0, mim = 0.0;
  for (int k = 0; k < D1*D2*D3; ++k){
    if (cabsd(re[k]) > mre) mre = cabsd(re[k]);
    if (cabsd(im[k]) > mim) mim = cabsd(im[k]);
  }
  CGData<L1,L2,L3> outv{};
  for (int k = 0; k < D1*D2*D3; ++k){
    double v = (mim > mre) ? im[k] : re[k];
    outv.w[k] = (cabsd(v) < 1e-10) ? 0.0f : (float)v;
  }
  return outv;
}

} // namespace cgc

template<int L1,int L2,int L3>
__device__ __forceinline__ void tp_path(const float* xa, const float* xb, float cmix, float* acc){
  constexpr cgc::CGData<L1,L2,L3> cg = cgc::make_cg<L1,L2,L3>();
  constexpr int D1 = 2*L1+1, D2 = 2*L2+1, D3 = 2*L3+1;
  float tmp[D3];
  #pragma unroll
  for (int m = 0; m < D3; ++m) tmp[m] = 0.0f;
  #pragma unroll
  for (int a = 0; a < D1; ++a){
    #pragma unroll
    for (int b = 0; b < D2; ++b){
      const float pr = xa[a] * xb[b];   // CSE'd across paths sharing operands
      #pragma unroll
      for (int m = 0; m < D3; ++m){
        const float W = cg.w[(a*D2+b)*D3 + m];
        if (W != 0.0f) tmp[m] += W * pr;   // constant-weight FMA; zeros DCE'd
      }
    }
  }
  #pragma unroll
  for (int m = 0; m < D3; ++m) acc[m] += cmix * tmp[m];  // runtime coeff applied ONCE
}

// Layout constants (match reference):
// OFF_IN  = [0, 64, 208, 368]; OFF_OUT = [0, 64, 208, 448, 672]
// mix bases (path order):
//  (0,0,0):0 (0,1,1):64 (0,2,2):112 (1,0,1):144 (1,1,0):192 (1,1,1):240 (1,1,2):288
//  (1,2,1):336 (1,2,2):368 (1,2,3):400 (2,0,2):432 (2,1,1):464 (2,1,2):496 (2,1,3):528
//  (2,2,0):560 (2,2,1):592 (2,2,2):624 (2,2,3):656
// keep chan: l0 -> i, l1 -> 64+i, l2 -> 112+i

#define NBLK 1024   // persistent blocks; groups grid-strided

__global__ __launch_bounds__(256, 4) void selfmix_kernel(
    const float* __restrict__ x, const float* __restrict__ keep,
    const float* __restrict__ mix, float* __restrict__ out, int n)
{
  // Wave w owns rows {2w, 2w+1} of each group: xs f4 [w*184,(w+1)*184),
  // os f4 [w*336,(w+1)*336). Slices are wave-private -> no barriers.
  __shared__ __align__(16) float xs[8 * 368];   // 11776 B
  __shared__ __align__(16) float os[8 * 672];   // 21504 B

  const int t = threadIdx.x;
  const int w = t >> 6;           // wave 0..3
  const int l = t & 63;           // lane
  const long long G = (n + 7) >> 3;   // total 8-row groups

  const float4* __restrict__ x4 = (const float4*)x;
  float4* __restrict__ o4 = (float4*)out;
  float4* xs4 = (float4*)xs;
  const float4* os4 = (const float4*)os;
  const long long nf4i = (long long)n * 92;
  const long long nf4o = (long long)n * 168;

  // ---- hoisted per-lane coefficients (loop-invariant) ----
  const int iA = l & 31;          // class-A channel for this lane
  float cmA[18];
  {
    const int MB[18] = {0,64,112,144,192,240,288,336,368,400,
                        432,464,496,528,560,592,624,656};
    #pragma unroll
    for (int k = 0; k < 18; ++k) cmA[k] = 0.5f * mix[MB[k] + iA];
  }
  const float kA0 = keep[iA], kA1 = keep[64+iA], kA2 = keep[112+iA];

  float cmB[6], kB0 = 0.f, kB1 = 0.f, cmC = 0.f, kC = 0.f;
  int iB = 0, iC = 0;
  if (l < 32){
    iB = 32 + (l & 15);
    const int MBb[6] = {0,64,144,192,240,288};
    #pragma unroll
    for (int k = 0; k < 6; ++k) cmB[k] = 0.5f * mix[MBb[k] + iB];
    kB0 = keep[iB]; kB1 = keep[64+iB];
  } else {
    iC = 48 + (l & 15);
    cmC = 0.5f * mix[iC]; kC = keep[iC];
  }

  const float4 F4Z = {0.f, 0.f, 0.f, 0.f};

  // ---- prologue: prefetch first group's wave slice (184 f4 = 64+64+56) ----
  long long g = blockIdx.x;
  float4 n0 = F4Z, n1 = F4Z, n2 = F4Z;
  if (g < G){
    const long long b = g*736 + (long long)w*184;
    if (b + l       < nf4i) n0 = x4[b + l];
    if (b + 64 + l  < nf4i) n1 = x4[b + 64 + l];
    if (l < 56 && b + 128 + l < nf4i) n2 = x4[b + 128 + l];
  }

  for (; g < G; g += NBLK){
    const float4 c0 = n0, c1 = n1, c2 = n2;

    // prefetch next group (flies under this group's compute+store)
    const long long gn = g + NBLK;
    if (gn < G){
      const long long b = gn*736 + (long long)w*184;
      if (b + l       < nf4i) n0 = x4[b + l];
      if (b + 64 + l  < nf4i) n1 = x4[b + 64 + l];
      if (l < 56 && b + 128 + l < nf4i) n2 = x4[b + 128 + l];
    }

    // ---- stage current group's slice into private xs ----
    {
      const int sb = w * 184;
      xs4[sb + l] = c0;
      xs4[sb + 64 + l] = c1;
      if (l < 56) xs4[sb + 128 + l] = c2;
    }
    // (wave-private: per-wave in-order LDS + compiler lgkm waits give RAW)

    const long long row0 = g * 8;

    // ---- class-A job: lane -> row 2w+(l>>5), channel l&31 ----
    {
      const int rowL = w*2 + (l >> 5);
      if (row0 + rowL < n){
        const float* xr = xs + rowL * 368;
        float*     orw  = os + rowL * 672;
        const int i = iA;
        float s = xr[i];
        float p[3], d[5];
        #pragma unroll
        for (int k = 0; k < 3; ++k) p[k] = xr[64 + i*3 + k];
        #pragma unroll
        for (int k = 0; k < 5; ++k) d[k] = xr[208 + i*5 + k];

        float o0 = 0.f;
        float o1[3] = {0.f,0.f,0.f};
        float o2[5] = {0.f,0.f,0.f,0.f,0.f};
        float o3[7] = {0.f,0.f,0.f,0.f,0.f,0.f,0.f};

        tp_path<0,0,0>(&s,&s, cmA[ 0], &o0);
        tp_path<0,1,1>(&s, p, cmA[ 1],  o1);
        tp_path<0,2,2>(&s, d, cmA[ 2],  o2);
        tp_path<1,0,1>( p,&s, cmA[ 3],  o1);
        tp_path<1,1,0>( p, p, cmA[ 4], &o0);
        tp_path<1,1,1>( p, p, cmA[ 5],  o1);
        tp_path<1,1,2>( p, p, cmA[ 6],  o2);
        tp_path<1,2,1>( p, d, cmA[ 7],  o1);
        tp_path<1,2,2>( p, d, cmA[ 8],  o2);
        tp_path<1,2,3>( p, d, cmA[ 9],  o3);
        tp_path<2,0,2>( d,&s, cmA[10],  o2);
        tp_path<2,1,1>( d, p, cmA[11],  o1);
        tp_path<2,1,2>( d, p, cmA[12],  o2);
        tp_path<2,1,3>( d, p, cmA[13],  o3);
        tp_path<2,2,0>( d, d, cmA[14], &o0);
        tp_path<2,2,1>( d, d, cmA[15],  o1);
        tp_path<2,2,2>( d, d, cmA[16],  o2);
        tp_path<2,2,3>( d, d, cmA[17],  o3);

        o0 += kA0 * s;
        #pragma unroll
        for (int k = 0; k < 3; ++k) o1[k] += kA1 * p[k];
        #pragma unroll
        for (int k = 0; k < 5; ++k) o2[k] += kA2 * d[k];

        orw[i] = o0;
        #pragma unroll
        for (int k = 0; k < 3; ++k) orw[ 64 + i*3 + k] = o1[k];
        #pragma unroll
        for (int k = 0; k < 5; ++k) orw[208 + i*5 + k] = o2[k];
        #pragma unroll
        for (int k = 0; k < 7; ++k) orw[448 + i*7 + k] = o3[k];
      }
    }

    // ---- class-B (lanes 0-31) / class-C (lanes 32-63) ----
    if (l < 32){
      const int rowL = w*2 + ((l >> 4) & 1);
      if (row0 + rowL < n){
        const float* xr = xs + rowL * 368;
        float*     orw  = os + rowL * 672;
        const int i = iB;
        float s = xr[i];
        float p[3];
        #pragma unroll
        for (int k = 0; k < 3; ++k) p[k] = xr[64 + i*3 + k];

        float o0 = 0.f;
        float o1[3] = {0.f,0.f,0.f};
        float o2[5] = {0.f,0.f,0.f,0.f,0.f};

        tp_path<0,0,0>(&s,&s, cmB[0], &o0);
        tp_path<0,1,1>(&s, p, cmB[1],  o1);
        tp_path<1,0,1>( p,&s, cmB[2],  o1);
        tp_path<1,1,0>( p, p, cmB[3], &o0);
        tp_path<1,1,1>( p, p, cmB[4],  o1);
        tp_path<1,1,2>( p, p, cmB[5],  o2);

        o0 += kB0 * s;
        #pragma unroll
        for (int k = 0; k < 3; ++k) o1[k] += kB1 * p[k];

        orw[i] = o0;
        #pragma unroll
        for (int k = 0; k < 3; ++k) orw[ 64 + i*3 + k] = o1[k];
        #pragma unroll
        for (int k = 0; k < 5; ++k) orw[208 + i*5 + k] = o2[k];
      }
    } else {
      const int rowL = w*2 + ((l >> 4) & 1);
      if (row0 + rowL < n){
        const float s = xs[rowL*368 + iC];
        float o0 = 0.f;
        tp_path<0,0,0>(&s,&s, cmC, &o0);
        o0 += kC * s;
        os[rowL*672 + iC] = o0;
      }
    }

    // ---- store private os slice: 336 f4 contiguous (2 rows) ----
    {
      const int sb = w * 336;
      const long long ob = g*1344 + (long long)w*336;
      #pragma unroll
      for (int k = 0; k < 5; ++k){
        if (ob + k*64 + l < nf4o) o4[ob + k*64 + l] = os4[sb + k*64 + l];
      }
      if (l < 16 && ob + 320 + l < nf4o) o4[ob + 320 + l] = os4[sb + 320 + l];
    }
  }
}

extern "C" void kernel_launch(void* const* d_in, const int* in_sizes, int n_in,
                              void* d_out, int out_size, void* d_ws, size_t ws_size,
                              hipStream_t stream)
{
  const float* x    = (const float*)d_in[0];
  const float* keep = (const float*)d_in[1];
  const float* mix  = (const float*)d_in[2];
  float* out = (float*)d_out;
  const int n = in_sizes[0] / 368;            // 32768
  const long long G = (n + 7) >> 3;           // 4096 groups
  const int blocks = (int)(G < NBLK ? G : NBLK);
  selfmix_kernel<<<blocks, 256, 0, stream>>>(x, keep, mix, out, n);
}

// Round 6
// 136.753 us; speedup vs baseline: 1.3526x; 1.3526x over previous
//
#include <hip/hip_runtime.h>

// SelfMixing: CG tensor-product self-coupling, diagonal in channel.
// V7: barrier-free, non-persistent, minimal-LDS.
//  - 4096 independent blocks x 256 thr (V5's proven shape; V6's persistence
//    regressed 2x and is dropped).
//  - Each WAVE owns 2 rows: loads its own 184-float4 x-slice into a private
//    LDS slice -> ZERO __syncthreads (no vmcnt/lgkm full drains). V6 proved
//    the wave-private pattern correct; here it is unbundled from persistence.
//  - No output staging: direct scattered dword stores (V1-proven ~free);
//    LDS drops 33KB -> 11.8KB -> 8 blocks/CU = 32 waves/CU (2x V5 occupancy).
// Diagnosis basis: traffic already ideal (V2 counters), VALU 12-20%, time
// invariant ~45us across I/O styles => latency/occupancy-bound.

namespace cgc {

struct cplx { double re, im; };
constexpr cplx cmul(cplx a, cplx b){ return {a.re*b.re - a.im*b.im, a.re*b.im + a.im*b.re}; }

constexpr double cfact(int n){ double r = 1.0; for (int i = 2; i <= n; ++i) r *= i; return r; }
constexpr double cabsd(double x){ return x < 0 ? -x : x; }

constexpr double csqrtd(double x){
  if (x <= 0.0) return 0.0;
  double g = x > 1.0 ? x : 1.0;
  for (int i = 0; i < 48; ++i) g = 0.5*(g + x/g);
  return g;
}

constexpr double SQRT2 = csqrtd(2.0);

constexpr double cg_complex(int l1,int m1,int l2,int m2,int l3,int m3){
  if (m1 + m2 != m3) return 0.0;
  int lo = l1 > l2 ? l1 - l2 : l2 - l1;
  if (l3 < lo || l3 > l1 + l2) return 0.0;
  double pre = csqrtd((2*l3+1) * cfact(l1+l2-l3)*cfact(l1-l2+l3)*cfact(-l1+l2+l3)/cfact(l1+l2+l3+1));
  pre *= csqrtd(cfact(l1+m1)*cfact(l1-m1)*cfact(l2+m2)*cfact(l2-m2)*cfact(l3+m3)*cfact(l3-m3));
  int kmin = 0;
  if (l2-l3-m1 > kmin) kmin = l2-l3-m1;
  if (l1-l3+m2 > kmin) kmin = l1-l3+m2;
  int kmax = l1+l2-l3;
  if (l1-m1 < kmax) kmax = l1-m1;
  if (l2+m2 < kmax) kmax = l2+m2;
  double s = 0.0;
  for (int k = kmin; k <= kmax; ++k){
    double d = cfact(k)*cfact(l1+l2-l3-k)*cfact(l1-m1-k)*cfact(l2+m2-k)
             * cfact(l3-l2+m1+k)*cfact(l3-l1-m2+k);
    s += ((k & 1) ? -1.0 : 1.0) / d;
  }
  return pre * s;
}

// U[r][c]: rows = real m' (r = m'+l), cols = complex m (c = m+l)
constexpr cplx Uent(int l, int r, int c){
  int m = r - l;
  if (m > 0){
    if (c ==  m + l) return { ((m & 1) ? -1.0 : 1.0)/SQRT2, 0.0 };
    if (c == -m + l) return { 1.0/SQRT2, 0.0 };
    return {0.0, 0.0};
  } else if (m == 0){
    if (c == l) return {1.0, 0.0};
    return {0.0, 0.0};
  } else {
    int ma = -m;
    if (c ==  m + l) return { 0.0, 1.0/SQRT2 };                       // 1j/sqrt2
    if (c == -m + l) return { 0.0, -(((ma & 1) ? -1.0 : 1.0))/SQRT2 };// -1j*(-1)^m/sqrt2
    return {0.0, 0.0};
  }
}

template<int L1,int L2,int L3>
struct CGData { float w[(2*L1+1)*(2*L2+1)*(2*L3+1)]; };

template<int L1,int L2,int L3>
constexpr CGData<L1,L2,L3> make_cg(){
  constexpr int D1 = 2*L1+1, D2 = 2*L2+1, D3 = 2*L3+1;
  cplx U1[D1*D1] = {}; cplx U2[D2*D2] = {}; cplx U3c[D3*D3] = {};
  for (int r = 0; r < D1; ++r) for (int c = 0; c < D1; ++c) U1[r*D1+c] = Uent(L1, r, c);
  for (int r = 0; r < D2; ++r) for (int c = 0; c < D2; ++c) U2[r*D2+c] = Uent(L2, r, c);
  for (int r = 0; r < D3; ++r) for (int c = 0; c < D3; ++c){
    cplx u = Uent(L3, r, c); u.im = -u.im; U3c[r*D3+c] = u;
  }
  double Cc[D1*D2*D3] = {};
  for (int m1 = -L1; m1 <= L1; ++m1)
    for (int m2 = -L2; m2 <= L2; ++m2){
      int m3 = m1 + m2;
      if (m3 < -L3 || m3 > L3) continue;
      Cc[((m1+L1)*D2 + (m2+L2))*D3 + (m3+L3)] = cg_complex(L1,m1,L2,m2,L3,m3);
    }
  double re[D1*D2*D3] = {}; double im[D1*D2*D3] = {};
  for (int a = 0; a < D1; ++a)
    for (int b = 0; b < D2; ++b)
      for (int c = 0; c < D3; ++c){
        double sre = 0.0, sim = 0.0;
        for (int m = 0; m < D1; ++m)
          for (int n = 0; n < D2; ++n){
            int o = m + n - L1 - L2 + L3;   // only nonzero Cc slice
            if (o < 0 || o >= D3) continue;
            double cc = Cc[(m*D2+n)*D3 + o];
            if (cc == 0.0) continue;
            cplx p = cmul(cmul(U1[a*D1+m], U2[b*D2+n]), U3c[c*D3+o]);
            sre += p.re * cc; sim += p.im * cc;
          }
        re[(a*D2+b)*D3+c] = sre; im[(a*D2+b)*D3+c] = sim;
      }
  double mre = 0.0, mim = 0.0;
  for (int k = 0; k < D1*D2*D3; ++k){
    if (cabsd(re[k]) > mre) mre = cabsd(re[k]);
    if (cabsd(im[k]) > mim) mim = cabsd(im[k]);
  }
  CGData<L1,L2,L3> outv{};
  for (int k = 0; k < D1*D2*D3; ++k){
    double v = (mim > mre) ? im[k] : re[k];
    outv.w[k] = (cabsd(v) < 1e-10) ? 0.0f : (float)v;
  }
  return outv;
}

} // namespace cgc

template<int L1,int L2,int L3>
__device__ __forceinline__ void tp_path(const float* xa, const float* xb, float cmix, float* acc){
  constexpr cgc::CGData<L1,L2,L3> cg = cgc::make_cg<L1,L2,L3>();
  constexpr int D1 = 2*L1+1, D2 = 2*L2+1, D3 = 2*L3+1;
  float tmp[D3];
  #pragma unroll
  for (int m = 0; m < D3; ++m) tmp[m] = 0.0f;
  #pragma unroll
  for (int a = 0; a < D1; ++a){
    #pragma unroll
    for (int b = 0; b < D2; ++b){
      const float pr = xa[a] * xb[b];   // CSE'd across paths sharing operands
      #pragma unroll
      for (int m = 0; m < D3; ++m){
        const float W = cg.w[(a*D2+b)*D3 + m];
        if (W != 0.0f) tmp[m] += W * pr;   // constant-weight FMA; zeros DCE'd
      }
    }
  }
  #pragma unroll
  for (int m = 0; m < D3; ++m) acc[m] += cmix * tmp[m];  // runtime coeff applied ONCE
}

// Layout constants (match reference):
// OFF_IN  = [0, 64, 208, 368]; OFF_OUT = [0, 64, 208, 448, 672]
// mix bases (path order):
//  (0,0,0):0 (0,1,1):64 (0,2,2):112 (1,0,1):144 (1,1,0):192 (1,1,1):240 (1,1,2):288
//  (1,2,1):336 (1,2,2):368 (1,2,3):400 (2,0,2):432 (2,1,1):464 (2,1,2):496 (2,1,3):528
//  (2,2,0):560 (2,2,1):592 (2,2,2):624 (2,2,3):656
// keep chan: l0 -> i, l1 -> 64+i, l2 -> 112+i

__global__ __launch_bounds__(256) void selfmix_kernel(
    const float* __restrict__ x, const float* __restrict__ keep,
    const float* __restrict__ mix, float* __restrict__ out, int n)
{
  // Wave w privately owns rows {2w, 2w+1}: xs f4 [w*184, (w+1)*184).
  // No __syncthreads anywhere. 11776 B LDS -> 8 blocks/CU (wave-limited).
  __shared__ __align__(16) float xs[8 * 368];

  const int t = threadIdx.x;
  const int w = t >> 6;            // wave 0..3
  const int l = t & 63;            // lane
  const long long g    = blockIdx.x;   // 8-row group
  const long long row0 = g * 8;

  const float4* __restrict__ x4 = (const float4*)x;
  float4* xs4 = (float4*)xs;
  const long long nf4i = (long long)n * 92;

  // ---- load wave's private slice: 184 f4 (rows 2w, 2w+1) ----
  {
    const long long b  = g * 736 + (long long)w * 184;
    const int       sb = w * 184;
    if (b + l       < nf4i) xs4[sb + l]       = x4[b + l];
    if (b + 64 + l  < nf4i) xs4[sb + 64 + l]  = x4[b + 64 + l];
    if (l < 56 && b + 128 + l < nf4i) xs4[sb + 128 + l] = x4[b + 128 + l];
  }
  // wave-private slice: compiler-inserted lgkmcnt waits order write->read.

  // ---- class-A job: every lane. row = 2w + (l>>5), channel i = l&31 ----
  {
    const int rowL = w*2 + (l >> 5);
    const int i    = l & 31;
    if (row0 + rowL < n){
      const float* xr   = xs + rowL * 368;
      float*       orow = out + (row0 + rowL) * 672;
      float s = xr[i];
      float p[3], d[5];
      #pragma unroll
      for (int k = 0; k < 3; ++k) p[k] = xr[64 + i*3 + k];
      #pragma unroll
      for (int k = 0; k < 5; ++k) d[k] = xr[208 + i*5 + k];

      float o0 = 0.f;
      float o1[3] = {0.f,0.f,0.f};
      float o2[5] = {0.f,0.f,0.f,0.f,0.f};
      float o3[7] = {0.f,0.f,0.f,0.f,0.f,0.f,0.f};

      tp_path<0,0,0>(&s,&s, 0.5f*mix[  0+i], &o0);
      tp_path<0,1,1>(&s, p, 0.5f*mix[ 64+i],  o1);
      tp_path<0,2,2>(&s, d, 0.5f*mix[112+i],  o2);
      tp_path<1,0,1>( p,&s, 0.5f*mix[144+i],  o1);
      tp_path<1,1,0>( p, p, 0.5f*mix[192+i], &o0);
      tp_path<1,1,1>( p, p, 0.5f*mix[240+i],  o1);
      tp_path<1,1,2>( p, p, 0.5f*mix[288+i],  o2);
      tp_path<1,2,1>( p, d, 0.5f*mix[336+i],  o1);
      tp_path<1,2,2>( p, d, 0.5f*mix[368+i],  o2);
      tp_path<1,2,3>( p, d, 0.5f*mix[400+i],  o3);
      tp_path<2,0,2>( d,&s, 0.5f*mix[432+i],  o2);
      tp_path<2,1,1>( d, p, 0.5f*mix[464+i],  o1);
      tp_path<2,1,2>( d, p, 0.5f*mix[496+i],  o2);
      tp_path<2,1,3>( d, p, 0.5f*mix[528+i],  o3);
      tp_path<2,2,0>( d, d, 0.5f*mix[560+i], &o0);
      tp_path<2,2,1>( d, d, 0.5f*mix[592+i],  o1);
      tp_path<2,2,2>( d, d, 0.5f*mix[624+i],  o2);
      tp_path<2,2,3>( d, d, 0.5f*mix[656+i],  o3);

      o0 += keep[i] * s;
      const float k1 = keep[64+i], k2 = keep[112+i];
      #pragma unroll
      for (int k = 0; k < 3; ++k) o1[k] += k1 * p[k];
      #pragma unroll
      for (int k = 0; k < 5; ++k) o2[k] += k2 * d[k];

      // direct scattered stores (V1-proven; lines completed by this block)
      orow[i] = o0;
      #pragma unroll
      for (int k = 0; k < 3; ++k) orow[ 64 + i*3 + k] = o1[k];
      #pragma unroll
      for (int k = 0; k < 5; ++k) orow[208 + i*5 + k] = o2[k];
      #pragma unroll
      for (int k = 0; k < 7; ++k) orow[448 + i*7 + k] = o3[k];
    }
  }

  // ---- class-B (lanes 0-31) / class-C (lanes 32-63), rows 2w + bit ----
  {
    const int rowL = w*2 + ((l >> 4) & 1);
    if (row0 + rowL < n){
      if (l < 32){
        const int i = 32 + (l & 15);
        const float* xr   = xs + rowL * 368;
        float*       orow = out + (row0 + rowL) * 672;
        float s = xr[i];
        float p[3];
        #pragma unroll
        for (int k = 0; k < 3; ++k) p[k] = xr[64 + i*3 + k];

        float o0 = 0.f;
        float o1[3] = {0.f,0.f,0.f};
        float o2[5] = {0.f,0.f,0.f,0.f,0.f};

        tp_path<0,0,0>(&s,&s, 0.5f*mix[  0+i], &o0);
        tp_path<0,1,1>(&s, p, 0.5f*mix[ 64+i],  o1);
        tp_path<1,0,1>( p,&s, 0.5f*mix[144+i],  o1);
        tp_path<1,1,0>( p, p, 0.5f*mix[192+i], &o0);
        tp_path<1,1,1>( p, p, 0.5f*mix[240+i],  o1);
        tp_path<1,1,2>( p, p, 0.5f*mix[288+i],  o2);

        o0 += keep[i] * s;
        const float k1 = keep[64+i];
        #pragma unroll
        for (int k = 0; k < 3; ++k) o1[k] += k1 * p[k];

        orow[i] = o0;
        #pragma unroll
        for (int k = 0; k < 3; ++k) orow[ 64 + i*3 + k] = o1[k];
        #pragma unroll
        for (int k = 0; k < 5; ++k) orow[208 + i*5 + k] = o2[k];
      } else {
        const int i = 48 + (l & 15);
        const float s = xs[rowL*368 + i];
        float o0 = 0.f;
        tp_path<0,0,0>(&s,&s, 0.5f*mix[0+i], &o0);
        o0 += keep[i] * s;
        out[(row0 + rowL) * 672 + i] = o0;
      }
    }
  }
}

extern "C" void kernel_launch(void* const* d_in, const int* in_sizes, int n_in,
                              void* d_out, int out_size, void* d_ws, size_t ws_size,
                              hipStream_t stream)
{
  const float* x    = (const float*)d_in[0];
  const float* keep = (const float*)d_in[1];
  const float* mix  = (const float*)d_in[2];
  float* out = (float*)d_out;
  const int n = in_sizes[0] / 368;        // 32768
  const int blocks = (n + 7) / 8;         // 4096
  selfmix_kernel<<<blocks, 256, 0, stream>>>(x, keep, mix, out, n);
}

// Round 7
// 132.183 us; speedup vs baseline: 1.3994x; 1.0346x over previous
//
#include <hip/hip_runtime.h>

// SelfMixing: CG tensor-product self-coupling, diagonal in channel.
// V8 = V5's memory behavior + V6's barrier-free body, non-persistent.
//  - 4096 independent blocks x 256 thr, 8 rows/block (V5's proven shape).
//  - Wave w privately owns rows {2w,2w+1}: loads its own 184-f4 xs slice,
//    computes A/B/C for its rows, stages full 672-float output rows in its
//    private os slice, stores 336 contiguous f4. ZERO __syncthreads
//    (V6 proved this body correct; V7 isolated V6's regression to the
//    persistence/prefetch loop, which is dropped).
// Composite-roofline context: timed region = 2x352MB fills (HBM-saturating)
// + our 134MB -> floor ~131us; V5 measured 131.6. This is the last 1-2us
// lever (barrier drains); traffic is already minimal.

namespace cgc {

struct cplx { double re, im; };
constexpr cplx cmul(cplx a, cplx b){ return {a.re*b.re - a.im*b.im, a.re*b.im + a.im*b.re}; }

constexpr double cfact(int n){ double r = 1.0; for (int i = 2; i <= n; ++i) r *= i; return r; }
constexpr double cabsd(double x){ return x < 0 ? -x : x; }

constexpr double csqrtd(double x){
  if (x <= 0.0) return 0.0;
  double g = x > 1.0 ? x : 1.0;
  for (int i = 0; i < 48; ++i) g = 0.5*(g + x/g);
  return g;
}

constexpr double SQRT2 = csqrtd(2.0);

constexpr double cg_complex(int l1,int m1,int l2,int m2,int l3,int m3){
  if (m1 + m2 != m3) return 0.0;
  int lo = l1 > l2 ? l1 - l2 : l2 - l1;
  if (l3 < lo || l3 > l1 + l2) return 0.0;
  double pre = csqrtd((2*l3+1) * cfact(l1+l2-l3)*cfact(l1-l2+l3)*cfact(-l1+l2+l3)/cfact(l1+l2+l3+1));
  pre *= csqrtd(cfact(l1+m1)*cfact(l1-m1)*cfact(l2+m2)*cfact(l2-m2)*cfact(l3+m3)*cfact(l3-m3));
  int kmin = 0;
  if (l2-l3-m1 > kmin) kmin = l2-l3-m1;
  if (l1-l3+m2 > kmin) kmin = l1-l3+m2;
  int kmax = l1+l2-l3;
  if (l1-m1 < kmax) kmax = l1-m1;
  if (l2+m2 < kmax) kmax = l2+m2;
  double s = 0.0;
  for (int k = kmin; k <= kmax; ++k){
    double d = cfact(k)*cfact(l1+l2-l3-k)*cfact(l1-m1-k)*cfact(l2+m2-k)
             * cfact(l3-l2+m1+k)*cfact(l3-l1-m2+k);
    s += ((k & 1) ? -1.0 : 1.0) / d;
  }
  return pre * s;
}

// U[r][c]: rows = real m' (r = m'+l), cols = complex m (c = m+l)
constexpr cplx Uent(int l, int r, int c){
  int m = r - l;
  if (m > 0){
    if (c ==  m + l) return { ((m & 1) ? -1.0 : 1.0)/SQRT2, 0.0 };
    if (c == -m + l) return { 1.0/SQRT2, 0.0 };
    return {0.0, 0.0};
  } else if (m == 0){
    if (c == l) return {1.0, 0.0};
    return {0.0, 0.0};
  } else {
    int ma = -m;
    if (c ==  m + l) return { 0.0, 1.0/SQRT2 };                       // 1j/sqrt2
    if (c == -m + l) return { 0.0, -(((ma & 1) ? -1.0 : 1.0))/SQRT2 };// -1j*(-1)^m/sqrt2
    return {0.0, 0.0};
  }
}

template<int L1,int L2,int L3>
struct CGData { float w[(2*L1+1)*(2*L2+1)*(2*L3+1)]; };

template<int L1,int L2,int L3>
constexpr CGData<L1,L2,L3> make_cg(){
  constexpr int D1 = 2*L1+1, D2 = 2*L2+1, D3 = 2*L3+1;
  cplx U1[D1*D1] = {}; cplx U2[D2*D2] = {}; cplx U3c[D3*D3] = {};
  for (int r = 0; r < D1; ++r) for (int c = 0; c < D1; ++c) U1[r*D1+c] = Uent(L1, r, c);
  for (int r = 0; r < D2; ++r) for (int c = 0; c < D2; ++c) U2[r*D2+c] = Uent(L2, r, c);
  for (int r = 0; r < D3; ++r) for (int c = 0; c < D3; ++c){
    cplx u = Uent(L3, r, c); u.im = -u.im; U3c[r*D3+c] = u;
  }
  double Cc[D1*D2*D3] = {};
  for (int m1 = -L1; m1 <= L1; ++m1)
    for (int m2 = -L2; m2 <= L2; ++m2){
      int m3 = m1 + m2;
      if (m3 < -L3 || m3 > L3) continue;
      Cc[((m1+L1)*D2 + (m2+L2))*D3 + (m3+L3)] = cg_complex(L1,m1,L2,m2,L3,m3);
    }
  double re[D1*D2*D3] = {}; double im[D1*D2*D3] = {};
  for (int a = 0; a < D1; ++a)
    for (int b = 0; b < D2; ++b)
      for (int c = 0; c < D3; ++c){
        double sre = 0.0, sim = 0.0;
        for (int m = 0; m < D1; ++m)
          for (int n = 0; n < D2; ++n){
            int o = m + n - L1 - L2 + L3;   // only nonzero Cc slice
            if (o < 0 || o >= D3) continue;
            double cc = Cc[(m*D2+n)*D3 + o];
            if (cc == 0.0) continue;
            cplx p = cmul(cmul(U1[a*D1+m], U2[b*D2+n]), U3c[c*D3+o]);
            sre += p.re * cc; sim += p.im * cc;
          }
        re[(a*D2+b)*D3+c] = sre; im[(a*D2+b)*D3+c] = sim;
      }
  double mre = 0.0, mim = 0.0;
  for (int k = 0; k < D1*D2*D3; ++k){
    if (cabsd(re[k]) > mre) mre = cabsd(re[k]);
    if (cabsd(im[k]) > mim) mim = cabsd(im[k]);
  }
  CGData<L1,L2,L3> outv{};
  for (int k = 0; k < D1*D2*D3; ++k){
    double v = (mim > mre) ? im[k] : re[k];
    outv.w[k] = (cabsd(v) < 1e-10) ? 0.0f : (float)v;
  }
  return outv;
}

} // namespace cgc

template<int L1,int L2,int L3>
__device__ __forceinline__ void tp_path(const float* xa, const float* xb, float cmix, float* acc){
  constexpr cgc::CGData<L1,L2,L3> cg = cgc::make_cg<L1,L2,L3>();
  constexpr int D1 = 2*L1+1, D2 = 2*L2+1, D3 = 2*L3+1;
  float tmp[D3];
  #pragma unroll
  for (int m = 0; m < D3; ++m) tmp[m] = 0.0f;
  #pragma unroll
  for (int a = 0; a < D1; ++a){
    #pragma unroll
    for (int b = 0; b < D2; ++b){
      const float pr = xa[a] * xb[b];   // CSE'd across paths sharing operands
      #pragma unroll
      for (int m = 0; m < D3; ++m){
        const float W = cg.w[(a*D2+b)*D3 + m];
        if (W != 0.0f) tmp[m] += W * pr;   // constant-weight FMA; zeros DCE'd
      }
    }
  }
  #pragma unroll
  for (int m = 0; m < D3; ++m) acc[m] += cmix * tmp[m];  // runtime coeff applied ONCE
}

// Layout constants (match reference):
// OFF_IN  = [0, 64, 208, 368]; OFF_OUT = [0, 64, 208, 448, 672]
// mix bases (path order):
//  (0,0,0):0 (0,1,1):64 (0,2,2):112 (1,0,1):144 (1,1,0):192 (1,1,1):240 (1,1,2):288
//  (1,2,1):336 (1,2,2):368 (1,2,3):400 (2,0,2):432 (2,1,1):464 (2,1,2):496 (2,1,3):528
//  (2,2,0):560 (2,2,1):592 (2,2,2):624 (2,2,3):656
// keep chan: l0 -> i, l1 -> 64+i, l2 -> 112+i
// Output-row coverage A∪B∪C = [0,672): P3 is a straight contiguous copy.

__global__ __launch_bounds__(256) void selfmix_kernel(
    const float* __restrict__ x, const float* __restrict__ keep,
    const float* __restrict__ mix, float* __restrict__ out, int n)
{
  // Wave w privately owns rows {2w, 2w+1}:
  //   xs f4 [w*184,(w+1)*184) ; os f4 [w*336,(w+1)*336). No barriers.
  __shared__ __align__(16) float xs[8 * 368];   // 11776 B
  __shared__ __align__(16) float os[8 * 672];   // 21504 B

  const int t = threadIdx.x;
  const int w = t >> 6;            // wave 0..3
  const int l = t & 63;            // lane
  const long long g    = blockIdx.x;
  const long long row0 = g * 8;

  const float4* __restrict__ x4 = (const float4*)x;
  float4* __restrict__ o4 = (float4*)out;
  float4* xs4 = (float4*)xs;
  const float4* os4 = (const float4*)os;
  const long long nf4i = (long long)n * 92;
  const long long nf4o = (long long)n * 168;

  // ---- P1: load wave's private x slice: 184 f4 (rows 2w, 2w+1) ----
  {
    const long long b  = g * 736 + (long long)w * 184;
    const int       sb = w * 184;
    if (b + l       < nf4i) xs4[sb + l]       = x4[b + l];
    if (b + 64 + l  < nf4i) xs4[sb + 64 + l]  = x4[b + 64 + l];
    if (l < 56 && b + 128 + l < nf4i) xs4[sb + 128 + l] = x4[b + 128 + l];
  }
  // intra-wave RAW ordered by compiler lgkmcnt waits (V6/V7-proven)

  // ---- P2a: class-A job, every lane: row 2w+(l>>5), channel l&31 ----
  {
    const int rowL = w*2 + (l >> 5);
    const int i    = l & 31;
    if (row0 + rowL < n){
      const float* xr  = xs + rowL * 368;
      float*       orw = os + rowL * 672;
      float s = xr[i];
      float p[3], d[5];
      #pragma unroll
      for (int k = 0; k < 3; ++k) p[k] = xr[64 + i*3 + k];
      #pragma unroll
      for (int k = 0; k < 5; ++k) d[k] = xr[208 + i*5 + k];

      float o0 = 0.f;
      float o1[3] = {0.f,0.f,0.f};
      float o2[5] = {0.f,0.f,0.f,0.f,0.f};
      float o3[7] = {0.f,0.f,0.f,0.f,0.f,0.f,0.f};

      tp_path<0,0,0>(&s,&s, 0.5f*mix[  0+i], &o0);
      tp_path<0,1,1>(&s, p, 0.5f*mix[ 64+i],  o1);
      tp_path<0,2,2>(&s, d, 0.5f*mix[112+i],  o2);
      tp_path<1,0,1>( p,&s, 0.5f*mix[144+i],  o1);
      tp_path<1,1,0>( p, p, 0.5f*mix[192+i], &o0);
      tp_path<1,1,1>( p, p, 0.5f*mix[240+i],  o1);
      tp_path<1,1,2>( p, p, 0.5f*mix[288+i],  o2);
      tp_path<1,2,1>( p, d, 0.5f*mix[336+i],  o1);
      tp_path<1,2,2>( p, d, 0.5f*mix[368+i],  o2);
      tp_path<1,2,3>( p, d, 0.5f*mix[400+i],  o3);
      tp_path<2,0,2>( d,&s, 0.5f*mix[432+i],  o2);
      tp_path<2,1,1>( d, p, 0.5f*mix[464+i],  o1);
      tp_path<2,1,2>( d, p, 0.5f*mix[496+i],  o2);
      tp_path<2,1,3>( d, p, 0.5f*mix[528+i],  o3);
      tp_path<2,2,0>( d, d, 0.5f*mix[560+i], &o0);
      tp_path<2,2,1>( d, d, 0.5f*mix[592+i],  o1);
      tp_path<2,2,2>( d, d, 0.5f*mix[624+i],  o2);
      tp_path<2,2,3>( d, d, 0.5f*mix[656+i],  o3);

      o0 += keep[i] * s;
      const float k1 = keep[64+i], k2 = keep[112+i];
      #pragma unroll
      for (int k = 0; k < 3; ++k) o1[k] += k1 * p[k];
      #pragma unroll
      for (int k = 0; k < 5; ++k) o2[k] += k2 * d[k];

      orw[i] = o0;
      #pragma unroll
      for (int k = 0; k < 3; ++k) orw[ 64 + i*3 + k] = o1[k];   // stride 3: conflict-free
      #pragma unroll
      for (int k = 0; k < 5; ++k) orw[208 + i*5 + k] = o2[k];   // stride 5: conflict-free
      #pragma unroll
      for (int k = 0; k < 7; ++k) orw[448 + i*7 + k] = o3[k];   // stride 7: conflict-free
    }
  }

  // ---- P2b/P2c: lanes 0-31 class-B, lanes 32-63 class-C; row 2w+((l>>4)&1) ----
  {
    const int rowL = w*2 + ((l >> 4) & 1);
    if (row0 + rowL < n){
      if (l < 32){
        const int i = 32 + (l & 15);
        const float* xr  = xs + rowL * 368;
        float*       orw = os + rowL * 672;
        float s = xr[i];
        float p[3];
        #pragma unroll
        for (int k = 0; k < 3; ++k) p[k] = xr[64 + i*3 + k];

        float o0 = 0.f;
        float o1[3] = {0.f,0.f,0.f};
        float o2[5] = {0.f,0.f,0.f,0.f,0.f};

        tp_path<0,0,0>(&s,&s, 0.5f*mix[  0+i], &o0);
        tp_path<0,1,1>(&s, p, 0.5f*mix[ 64+i],  o1);
        tp_path<1,0,1>( p,&s, 0.5f*mix[144+i],  o1);
        tp_path<1,1,0>( p, p, 0.5f*mix[192+i], &o0);
        tp_path<1,1,1>( p, p, 0.5f*mix[240+i],  o1);
        tp_path<1,1,2>( p, p, 0.5f*mix[288+i],  o2);

        o0 += keep[i] * s;
        const float k1 = keep[64+i];
        #pragma unroll
        for (int k = 0; k < 3; ++k) o1[k] += k1 * p[k];

        orw[i] = o0;
        #pragma unroll
        for (int k = 0; k < 3; ++k) orw[ 64 + i*3 + k] = o1[k];
        #pragma unroll
        for (int k = 0; k < 5; ++k) orw[208 + i*5 + k] = o2[k];
      } else {
        const int i = 48 + (l & 15);
        const float s = xs[rowL*368 + i];
        float o0 = 0.f;
        tp_path<0,0,0>(&s,&s, 0.5f*mix[0+i], &o0);
        o0 += keep[i] * s;
        os[rowL*672 + i] = o0;
      }
    }
  }

  // ---- P3: store wave's private os slice: 336 contiguous f4 (2 rows) ----
  {
    const int       sb = w * 336;
    const long long ob = g * 1344 + (long long)w * 336;
    #pragma unroll
    for (int k = 0; k < 5; ++k){
      if (ob + k*64 + l < nf4o) o4[ob + k*64 + l] = os4[sb + k*64 + l];
    }
    if (l < 16 && ob + 320 + l < nf4o) o4[ob + 320 + l] = os4[sb + 320 + l];
  }
}

extern "C" void kernel_launch(void* const* d_in, const int* in_sizes, int n_in,
                              void* d_out, int out_size, void* d_ws, size_t ws_size,
                              hipStream_t stream)
{
  const float* x    = (const float*)d_in[0];
  const float* keep = (const float*)d_in[1];
  const float* mix  = (const float*)d_in[2];
  float* out = (float*)d_out;
  const int n = in_sizes[0] / 368;        // 32768
  const int blocks = (n + 7) / 8;         // 4096
  selfmix_kernel<<<blocks, 256, 0, stream>>>(x, keep, mix, out, n);
}